// Round 9
// baseline (3733.981 us; speedup 1.0000x reference)
//
#include <hip/hip_runtime.h>

#define HH 128
#define WW 128
#define HWP (HH*WW)
#define NC 64
#define NB 2
#define NN 5
#define OFFC 144
#define NKC 18                    // K-chunks of 32 per 576-K conv pass

typedef __attribute__((ext_vector_type(8))) _Float16 half8;
typedef __attribute__((ext_vector_type(4))) float floatx4;
typedef __attribute__((ext_vector_type(2))) float floatx2;

// out[b, center=2] = x_center
__global__ __launch_bounds__(256) void copy_center_k(const float* __restrict__ xc,
                                                     float* __restrict__ out) {
    int idx = blockIdx.x * 256 + threadIdx.x;
    const int total = NB * 3 * HWP;
    if (idx >= total) return;
    int b = idx / (3 * HWP);
    int r = idx - b * 3 * HWP;
    out[(size_t)((b * NN + 2) * 3) * HWP + r] = xc[idx];
}

// Repack planar pf frame -> channel-last [px][64]. is_ref: blockIdx.y = b (center frame);
// else blockIdx.y = jl (supp frame of job job0+jl). LDS 64x65 transpose tile (2-way banks).
__global__ __launch_bounds__(256) void repack_k(const float* __restrict__ pf,
                                                float* __restrict__ dst, int job0, int is_ref)
{
    __shared__ float T[64][65];
    const int jl = blockIdx.y;
    const float* src;
    if (is_ref) {
        src = pf + (size_t)((jl * NN + 2) * NC) * HWP;
    } else {
        int jg = job0 + jl;
        int b = jg & 1, fi = jg >> 1;
        int frame = fi + (fi >= 2 ? 1 : 0);
        src = pf + (size_t)((b * NN + frame) * NC) * HWP;
    }
    float* d = dst + (size_t)jl * NC * HWP;
    const int p0 = blockIdx.x * 64;
    const int tid = threadIdx.x;
    const int lx = tid & 63, cg4 = tid >> 6;
#pragma unroll
    for (int cc = 0; cc < 16; ++cc) {
        int c = cc * 4 + cg4;
        T[c][lx] = src[(size_t)c * HWP + p0 + lx];
    }
    __syncthreads();
    const int px = tid >> 2, c0 = (tid & 3) * 16;
#pragma unroll
    for (int j = 0; j < 4; ++j) {
        floatx4 v = { T[c0 + j*4 + 0][px], T[c0 + j*4 + 1][px],
                      T[c0 + j*4 + 2][px], T[c0 + j*4 + 3][px] };
        *(floatx4*)(d + (size_t)(p0 + px) * 64 + c0 + j*4) = v;
    }
}

// Weight preprocessor, SPLIT-fp16 (unchanged from R8): w[co][cin_src][9] ->
// wp[ct][kc][{hi,lo}][lane][8], k = kc*32 + (lane>>4)*8 + j, kk = k>>6, ci = k&63.
__global__ __launch_bounds__(256) void prew_k(const float* __restrict__ w,
                                              _Float16* __restrict__ wp,
                                              int nct, int ci_off, int cin_src)
{
    int idx = blockIdx.x * 256 + threadIdx.x;
    if (idx >= nct * NKC * 64) return;
    int lane = idx & 63;
    int kc = (idx >> 6) % NKC;
    int ct = (idx >> 6) / NKC;
    int m = lane & 15, quad = lane >> 4;
    int co = ct * 16 + m;
    union { half8 v; _Float16 e[8]; } ph, pl;
#pragma unroll
    for (int j = 0; j < 8; ++j) {
        int k = kc * 32 + quad * 8 + j;
        int kk = k >> 6, ci = k & 63;
        float f = w[((size_t)co * cin_src + ci_off + ci) * 9 + kk];
        _Float16 h = (_Float16)f;
        ph.e[j] = h; pl.e[j] = (_Float16)(f - (float)h);
    }
    size_t base = (size_t)((ct * NKC + kc) * 2) * 512;
    *(half8*)(wp + base + lane * 8) = ph.v;
    *(half8*)(wp + base + 512 + lane * 8) = pl.v;
}

// SPLIT-fp16 MFMA 3x3 conv (R8-proven core), CHANNEL-LAST src & dst.
// Block = 16x8 px tile, 4 waves; wave wq -> rows {2wq,2wq+1}. Full K=576 halo
// resident as fp16 hi+lo planes [cb(8)][hy][hx][ci8(8)].
// SRCMODE 0: feature buf (jl). 1: R ref (b). 2: S supp (jl). ADD: out += (cr pass 2).
template<int NCT, int SRCMODE, int ADD>
__global__ __launch_bounds__(256, 2) void mconv_k(
    const float* __restrict__ src, const float* __restrict__ R,
    const float* __restrict__ S, const _Float16* __restrict__ wp,
    const float* __restrict__ bias, float* __restrict__ out, int job0)
{
    constexpr int PL = 1456;              // 10*18*8 = 1440 + 16 pad (fp16 elems)
    constexpr int Ct = NCT * 16;
    const int jl = blockIdx.y, jg = job0 + jl;
    const int b = jg & 1;
    const int tile = blockIdx.x;          // 8 in x, 16 in y
    const int ty0 = (tile >> 3) << 3, tx0 = (tile & 7) << 4;
    const int tid = threadIdx.x;
    const int lane = tid & 63;
    const int wq = __builtin_amdgcn_readfirstlane(tid >> 6);
    const int n = lane & 15, quad = lane >> 4;

    const float* s0;
    if (SRCMODE == 0)      s0 = src + (size_t)jl * NC * HWP;
    else if (SRCMODE == 1) s0 = R + (size_t)b * NC * HWP;
    else                   s0 = S + (size_t)jl * NC * HWP;

    __shared__ _Float16 hh[8 * PL];
    __shared__ _Float16 ll[8 * PL];

    // ---- stage halo (180 px x 64 ci), channel-last coalesced float4 reads ----
    for (int t = tid; t < 360; t += 256) {
        int px = t >> 1, hf = t & 1;      // hf: ci 0-31 / 32-63
        int hy = px / 18, hx = px - hy * 18;
        int gy = ty0 - 1 + hy, gx = tx0 - 1 + hx;
        bool ok = (gy >= 0 && gy < HH && gx >= 0 && gx < WW);
        const float* sp = s0 + (ok ? ((size_t)(gy * WW + gx) * 64) : 0) + hf * 32;
        int lb = px * 8;
#pragma unroll
        for (int c = 0; c < 4; ++c) {
            int cb = hf * 4 + c;
            floatx4 f0 = {0.f,0.f,0.f,0.f}, f1 = {0.f,0.f,0.f,0.f};
            if (ok) {
                f0 = *(const floatx4*)(sp + c * 8);
                f1 = *(const floatx4*)(sp + c * 8 + 4);
            }
            union { half8 v; _Float16 e[8]; } ph, pl;
#pragma unroll
            for (int j = 0; j < 4; ++j) {
                _Float16 h0 = (_Float16)f0[j], h1 = (_Float16)f1[j];
                ph.e[j] = h0;     ph.e[j+4] = h1;
                pl.e[j] = (_Float16)(f0[j] - (float)h0);
                pl.e[j+4] = (_Float16)(f1[j] - (float)h1);
            }
            *(half8*)&hh[cb * PL + lb] = ph.v;
            *(half8*)&ll[cb * PL + lb] = pl.v;
        }
    }
    __syncthreads();

    // ---- compute ----
    for (int ct = 0; ct < NCT; ++ct) {
        half8 Ah[NKC], Al[NKC];
#pragma unroll
        for (int kc = 0; kc < NKC; ++kc) {
            size_t base = (size_t)((ct * NKC + kc) * 2) * 512;
            Ah[kc] = *(const half8*)(wp + base + lane * 8);
            Al[kc] = *(const half8*)(wp + base + 512 + lane * 8);
        }
        const floatx4 b4 = *(const floatx4*)(bias + ct * 16 + quad * 4);
#pragma unroll
        for (int r = 0; r < 2; ++r) {
            const int y = wq * 2 + r;
            floatx4 acc = {0.f, 0.f, 0.f, 0.f};
#pragma unroll
            for (int kc = 0; kc < NKC; ++kc) {
                const int kk = kc >> 1;
                const int dy = kk / 3, dx = kk % 3;
                const int cb = ((kc & 1) << 2) + quad;
                const int ix = cb * PL + ((y + dy) * 18 + n + dx) * 8;
                half8 Bh = *(const half8*)&hh[ix];
                half8 Bl = *(const half8*)&ll[ix];
                acc = __builtin_amdgcn_mfma_f32_16x16x32_f16(Ah[kc], Bh, acc, 0, 0, 0);
                acc = __builtin_amdgcn_mfma_f32_16x16x32_f16(Ah[kc], Bl, acc, 0, 0, 0);
                acc = __builtin_amdgcn_mfma_f32_16x16x32_f16(Al[kc], Bh, acc, 0, 0, 0);
            }
            const int oy = ty0 + y, ox = tx0 + n;
            float* op = out + ((size_t)jl * HWP + (size_t)oy * WW + ox) * Ct
                            + ct * 16 + quad * 4;
            if (ADD) {
                floatx4 old = *(const floatx4*)op;
                acc += old;
            } else {
                acc += b4;
            }
            *(floatx4*)op = acc;
        }
    }
}

// Deformable conv (v1, DG=8, Cg=8). CHANNEL-LAST input/offsets/output.
// Block = 8x8 px tile x 4 waves; wave q -> couts [16q,16q+16). Phase A: vectorized
// bilinear gathers (2x dwordx4 per corner-group); phase B: R3-proven fp32 contraction.
__global__ __launch_bounds__(256) void deform_k(
    const float* __restrict__ in, const float* __restrict__ off,
    const float* __restrict__ w, const float* __restrict__ bias,
    float* __restrict__ out, int job0, int supp_mode, const float* __restrict__ S)
{
    const int jl = blockIdx.y;
    const int tile = blockIdx.x;          // 16x16 tiles of 8x8
    const int ty0 = (tile >> 4) << 3, tx0 = (tile & 15) << 3;
    const int tid = threadIdx.x;
    const int p = tid & 63;
    const int q = __builtin_amdgcn_readfirstlane(tid >> 6);

    const float* ibase = supp_mode ? (S + (size_t)jl * NC * HWP)
                                   : (in + (size_t)jl * NC * HWP);
    const float* obase = off + (size_t)jl * OFFC * HWP;

    __shared__ float samp[64 * 73];
    float acc[16];
#pragma unroll
    for (int o = 0; o < 16; ++o) acc[o] = bias[q * 16 + o];

    for (int g = 0; g < 8; ++g) {
        __syncthreads();
        // ---- phase A: vectorized bilinear sampling into LDS ----
        for (int tk = tid; tk < 576; tk += 256) {
            int kk = tk >> 6;
            int pp = tk & 63;
            int yy = ty0 + (pp >> 3), xx = tx0 + (pp & 7);
            floatx2 o2 = *(const floatx2*)(obase + (size_t)(yy * WW + xx) * OFFC
                                           + (g * 9 + kk) * 2);
            float pyf = (float)(yy + (kk / 3) - 1) + o2[0];
            float pxf = (float)(xx + (kk % 3) - 1) + o2[1];
            float fy = floorf(pyf), fx = floorf(pxf);
            float wy = pyf - fy, wx = pxf - fx;
            int y0 = (int)fy, x0 = (int)fx;
            int y1 = y0 + 1, x1 = x0 + 1;
            float m00 = (y0 >= 0 && y0 < HH && x0 >= 0 && x0 < WW) ? 1.f : 0.f;
            float m01 = (y0 >= 0 && y0 < HH && x1 >= 0 && x1 < WW) ? 1.f : 0.f;
            float m10 = (y1 >= 0 && y1 < HH && x0 >= 0 && x0 < WW) ? 1.f : 0.f;
            float m11 = (y1 >= 0 && y1 < HH && x1 >= 0 && x1 < WW) ? 1.f : 0.f;
            float w00 = (1.f - wy) * (1.f - wx) * m00;
            float w01 = (1.f - wy) * wx * m01;
            float w10 = wy * (1.f - wx) * m10;
            float w11 = wy * wx * m11;
            int cy0 = min(max(y0, 0), HH - 1), cy1 = min(max(y1, 0), HH - 1);
            int cx0 = min(max(x0, 0), WW - 1), cx1 = min(max(x1, 0), WW - 1);
            const float* p00 = ibase + (size_t)(cy0 * WW + cx0) * 64 + g * 8;
            const float* p01 = ibase + (size_t)(cy0 * WW + cx1) * 64 + g * 8;
            const float* p10 = ibase + (size_t)(cy1 * WW + cx0) * 64 + g * 8;
            const float* p11 = ibase + (size_t)(cy1 * WW + cx1) * 64 + g * 8;
            floatx4 a0 = *(const floatx4*)p00,        a1 = *(const floatx4*)(p00 + 4);
            floatx4 b0 = *(const floatx4*)p01,        b1 = *(const floatx4*)(p01 + 4);
            floatx4 c0 = *(const floatx4*)p10,        c1 = *(const floatx4*)(p10 + 4);
            floatx4 d0 = *(const floatx4*)p11,        d1 = *(const floatx4*)(p11 + 4);
            floatx4 s0 = a0 * w00 + b0 * w01 + c0 * w10 + d0 * w11;
            floatx4 s1 = a1 * w00 + b1 * w01 + c1 * w10 + d1 * w11;
            float* sb = &samp[pp * 73 + kk];
#pragma unroll
            for (int j = 0; j < 4; ++j) {
                sb[j * 9] = s0[j];
                sb[(j + 4) * 9] = s1[j];
            }
        }
        __syncthreads();
        // ---- phase B: fp32 contraction (16 couts per wave) ----
#pragma unroll
        for (int cg = 0; cg < 8; ++cg) {
            int cin = g * 8 + cg;
            const float* wrow = w + ((size_t)(q * 16) * NC + cin) * 9;
#pragma unroll
            for (int kk = 0; kk < 9; ++kk) {
                float s = samp[p * 73 + cg * 9 + kk];
#pragma unroll
                for (int o = 0; o < 16; ++o)
                    acc[o] = fmaf(wrow[(size_t)o * NC * 9 + kk], s, acc[o]);
            }
        }
    }
    const int oy = ty0 + (p >> 3), ox = tx0 + (p & 7);
    float* op = out + ((size_t)jl * HWP + (size_t)oy * WW + ox) * 64 + q * 16;
#pragma unroll
    for (int s = 0; s < 4; ++s) {
        floatx4 v = { acc[s*4], acc[s*4+1], acc[s*4+2], acc[s*4+3] };
        *(floatx4*)(op + s * 4) = v;
    }
}

// rec conv (64 -> 3): fp32, channel-last input. Writes d_out (planar, as required).
__global__ __launch_bounds__(256) void conv3x3_rec_k(
    const float* __restrict__ in, const float* __restrict__ w,
    const float* __restrict__ bias, float* __restrict__ out, int job0)
{
    constexpr int CB = 8;
    constexpr int PITCH = 48;
    constexpr int CH = 18 * PITCH;
    const int jl = blockIdx.y, jg = job0 + jl;
    const int b = jg & 1, fi = jg >> 1;
    const int frame = fi + (fi >= 2 ? 1 : 0);
    const int tile = blockIdx.x;
    const int ty0 = (tile >> 3) << 4, tx0 = (tile & 7) << 4;
    const int tid = threadIdx.x;
    const int tx = tid & 15, ty = tid >> 4;
    const float* srcA = in + (size_t)jl * NC * HWP;

    __shared__ float lds[CB * CH];
    float acc[3] = {bias[0], bias[1], bias[2]};

    for (int cb = 0; cb < NC; cb += CB) {
        __syncthreads();
        for (int e = tid; e < CB * 324; e += 256) {
            int c = e & 7;
            int r = e >> 3;
            int iy = r / 18, ix = r - iy * 18;
            int gy = ty0 - 1 + iy, gx = tx0 - 1 + ix;
            float v = 0.f;
            if (gy >= 0 && gy < HH && gx >= 0 && gx < WW)
                v = srcA[(size_t)(gy * WW + gx) * 64 + cb + c];
            lds[c * CH + iy * PITCH + ix] = v;
        }
        __syncthreads();
#pragma unroll
        for (int c = 0; c < CB; ++c) {
            float t[9];
#pragma unroll
            for (int dy = 0; dy < 3; ++dy)
#pragma unroll
                for (int dx = 0; dx < 3; ++dx)
                    t[dy * 3 + dx] = lds[c * CH + (ty + dy) * PITCH + (tx + dx)];
            int ci = cb + c;
#pragma unroll
            for (int o = 0; o < 3; ++o) {
                const float* wo = w + ((size_t)o * NC + ci) * 9;
#pragma unroll
                for (int kk = 0; kk < 9; ++kk)
                    acc[o] = fmaf(wo[kk], t[kk], acc[o]);
            }
        }
    }
    const int oy = ty0 + ty, ox = tx0 + tx;
#pragma unroll
    for (int o = 0; o < 3; ++o)
        out[((size_t)(b * NN + frame) * 3 + o) * HWP + oy * WW + ox] = acc[o];
}

extern "C" void kernel_launch(void* const* d_in, const int* in_sizes, int n_in,
                              void* d_out, int out_size, void* d_ws, size_t ws_size,
                              hipStream_t stream)
{
    const float* pf    = (const float*)d_in[0];
    const float* xc    = (const float*)d_in[1];
    const float* cr_w  = (const float*)d_in[2];
    const float* cr_b  = (const float*)d_in[3];
    const float* ow[4] = {(const float*)d_in[4],  (const float*)d_in[8],
                          (const float*)d_in[12], (const float*)d_in[16]};
    const float* ob[4] = {(const float*)d_in[5],  (const float*)d_in[9],
                          (const float*)d_in[13], (const float*)d_in[17]};
    const float* dw[4] = {(const float*)d_in[6],  (const float*)d_in[10],
                          (const float*)d_in[14], (const float*)d_in[18]};
    const float* db[4] = {(const float*)d_in[7],  (const float*)d_in[11],
                          (const float*)d_in[15], (const float*)d_in[19]};
    const float* rec_w = (const float*)d_in[20];
    const float* rec_b = (const float*)d_in[21];
    float* out = (float*)d_out;

    // ws layout: [wp split-fp16][R ref-cl 2][S supp-cl JC][A JC][Bb JC][O JC]
    const size_t WPC = (size_t)4 * NKC * 1024;
    const size_t WPO = (size_t)9 * NKC * 1024;
    _Float16* wp_cr0 = (_Float16*)d_ws;
    _Float16* wp_cr1 = wp_cr0 + WPC;
    _Float16* wp_of[4];
    _Float16* curh = wp_cr1 + WPC;
    for (int i = 0; i < 4; ++i) { wp_of[i] = curh; curh += WPO; }
    size_t wp_bytes = (size_t)((char*)curh - (char*)d_ws);

    const size_t fplane = (size_t)NC * HWP;            // floats
    const size_t oplane = (size_t)OFFC * HWP;
    int JC = 8;
    while (JC > 1 &&
           wp_bytes + (2 + 3 * (size_t)JC) * fplane * 4 + (size_t)JC * oplane * 4 > ws_size)
        JC >>= 1;
    float* R  = (float*)curh;
    float* S  = R  + 2 * fplane;
    float* A  = S  + (size_t)JC * fplane;
    float* Bb = A  + (size_t)JC * fplane;
    float* O  = Bb + (size_t)JC * fplane;

    // ---- weight preprocessing + ref repack (every call; ws re-poisoned) ----
    {
        int nc4 = 4 * NKC * 64, nc9 = 9 * NKC * 64;
        dim3 b4((nc4 + 255) / 256), b9((nc9 + 255) / 256);
        prew_k<<<b4, 256, 0, stream>>>(cr_w, wp_cr0, 4, 0, 128);
        prew_k<<<b4, 256, 0, stream>>>(cr_w, wp_cr1, 4, 64, 128);
        for (int i = 0; i < 4; ++i)
            prew_k<<<b9, 256, 0, stream>>>(ow[i], wp_of[i], 9, 0, 64);
        repack_k<<<dim3(256, 2), 256, 0, stream>>>(pf, R, 0, 1);
    }

    copy_center_k<<<dim3((NB * 3 * HWP + 255) / 256), 256, 0, stream>>>(xc, out);

    for (int job0 = 0; job0 < 8; job0 += JC) {
        dim3 blk(256);
        dim3 gconv(128, JC), gdef(256, JC), grec(64, JC);
        repack_k<<<dim3(256, JC), blk, 0, stream>>>(pf, S, job0, 0);
        // fea1 = cr_conv(concat(ref, supp)) : two K=576 passes (ref, then supp ADD)
        mconv_k<4, 1, 0><<<gconv, blk, 0, stream>>>(nullptr, R, S, wp_cr0, cr_b, A, job0);
        mconv_k<4, 2, 1><<<gconv, blk, 0, stream>>>(nullptr, R, S, wp_cr1, cr_b, A, job0);
        // off1(fea1); fea2 = deform(fea1)
        mconv_k<9, 0, 0><<<gconv, blk, 0, stream>>>(A, R, S, wp_of[0], ob[0], O, job0);
        deform_k<<<gdef, blk, 0, stream>>>(A, O, dw[0], db[0], Bb, job0, 0, S);
        // off2(fea2); fea3 = deform(fea2)
        mconv_k<9, 0, 0><<<gconv, blk, 0, stream>>>(Bb, R, S, wp_of[1], ob[1], O, job0);
        deform_k<<<gdef, blk, 0, stream>>>(Bb, O, dw[1], db[1], A, job0, 0, S);
        // off3(fea3); fea4 = deform(supp)
        mconv_k<9, 0, 0><<<gconv, blk, 0, stream>>>(A, R, S, wp_of[2], ob[2], O, job0);
        deform_k<<<gdef, blk, 0, stream>>>(nullptr, O, dw[2], db[2], Bb, job0, 1, S);
        // off4(fea4); aligned = deform(fea4)
        mconv_k<9, 0, 0><<<gconv, blk, 0, stream>>>(Bb, R, S, wp_of[3], ob[3], O, job0);
        deform_k<<<gdef, blk, 0, stream>>>(Bb, O, dw[3], db[3], A, job0, 0, S);
        // out[b, frame] = rec_conv(aligned)
        conv3x3_rec_k<<<grec, blk, 0, stream>>>(A, rec_w, rec_b, out, job0);
    }
}

// Round 10
// 1800.833 us; speedup vs baseline: 2.0735x; 2.0735x over previous
//
#include <hip/hip_runtime.h>

#define HH 128
#define WW 128
#define HWP (HH*WW)
#define NC 64
#define NB 2
#define NN 5
#define OFFC 144
#define NKC 18                    // K-chunks of 32 per 576-K conv pass

typedef __attribute__((ext_vector_type(8))) _Float16 half8;
typedef __attribute__((ext_vector_type(4))) float floatx4;
typedef __attribute__((ext_vector_type(2))) float floatx2;

// out[b, center=2] = x_center
__global__ __launch_bounds__(256) void copy_center_k(const float* __restrict__ xc,
                                                     float* __restrict__ out) {
    int idx = blockIdx.x * 256 + threadIdx.x;
    const int total = NB * 3 * HWP;
    if (idx >= total) return;
    int b = idx / (3 * HWP);
    int r = idx - b * 3 * HWP;
    out[(size_t)((b * NN + 2) * 3) * HWP + r] = xc[idx];
}

// Repack planar pf frame -> channel-last [px][64]. is_ref: blockIdx.y = b (center frame);
// else blockIdx.y = jl (supp frame of job job0+jl). LDS 64x65 transpose tile.
__global__ __launch_bounds__(256) void repack_k(const float* __restrict__ pf,
                                                float* __restrict__ dst, int job0, int is_ref)
{
    __shared__ float T[64][65];
    const int jl = blockIdx.y;
    const float* src;
    if (is_ref) {
        src = pf + (size_t)((jl * NN + 2) * NC) * HWP;
    } else {
        int jg = job0 + jl;
        int b = jg & 1, fi = jg >> 1;
        int frame = fi + (fi >= 2 ? 1 : 0);
        src = pf + (size_t)((b * NN + frame) * NC) * HWP;
    }
    float* d = dst + (size_t)jl * NC * HWP;
    const int p0 = blockIdx.x * 64;
    const int tid = threadIdx.x;
    const int lx = tid & 63, cg4 = tid >> 6;
#pragma unroll
    for (int cc = 0; cc < 16; ++cc) {
        int c = cc * 4 + cg4;
        T[c][lx] = src[(size_t)c * HWP + p0 + lx];
    }
    __syncthreads();
    const int px = tid >> 2, c0 = (tid & 3) * 16;
#pragma unroll
    for (int j = 0; j < 4; ++j) {
        floatx4 v = { T[c0 + j*4 + 0][px], T[c0 + j*4 + 1][px],
                      T[c0 + j*4 + 2][px], T[c0 + j*4 + 3][px] };
        *(floatx4*)(d + (size_t)(p0 + px) * 64 + c0 + j*4) = v;
    }
}

// Weight preprocessor, SPLIT-fp16: w[co][cin_src][9] -> wp[ct][kc][{hi,lo}][lane][8],
// k = kc*32 + (lane>>4)*8 + j.
// mode 0 (conv, nkc=18):   kk = k>>6, ci = k&63 (+ci_off).
// mode 1 (deform, nkc=20): r = k/160, kr = k%160; kr<144: g = r*2 + kr/72,
//                          kk = (kr%72)>>3, cg = kr&7, ci = g*8+cg; else zero pad.
__global__ __launch_bounds__(256) void prew_k(const float* __restrict__ w,
                                              _Float16* __restrict__ wp,
                                              int nct, int nkc, int mode,
                                              int ci_off, int cin_src)
{
    int idx = blockIdx.x * 256 + threadIdx.x;
    if (idx >= nct * nkc * 64) return;
    int lane = idx & 63;
    int kc = (idx >> 6) % nkc;
    int ct = (idx >> 6) / nkc;
    int m = lane & 15, quad = lane >> 4;
    int co = ct * 16 + m;
    union { half8 v; _Float16 e[8]; } ph, pl;
#pragma unroll
    for (int j = 0; j < 8; ++j) {
        int k = kc * 32 + quad * 8 + j;
        float f = 0.f;
        if (mode == 0) {
            int kk = k >> 6, ci = k & 63;
            f = w[((size_t)co * cin_src + ci_off + ci) * 9 + kk];
        } else {
            int r = k / 160, kr = k - r * 160;
            if (kr < 144) {
                int g = r * 2 + kr / 72;
                int rr = kr % 72;
                int kk = rr >> 3, cg = rr & 7;
                f = w[((size_t)co * cin_src + g * 8 + cg) * 9 + kk];
            }
        }
        _Float16 h = (_Float16)f;
        ph.e[j] = h; pl.e[j] = (_Float16)(f - (float)h);
    }
    size_t base = (size_t)((ct * nkc + kc) * 2) * 512;
    *(half8*)(wp + base + lane * 8) = ph.v;
    *(half8*)(wp + base + 512 + lane * 8) = pl.v;
}

// SPLIT-fp16 MFMA 3x3 conv (R8/R9-proven), CHANNEL-LAST src & dst. Unchanged from R9.
template<int NCT, int SRCMODE, int ADD>
__global__ __launch_bounds__(256, 2) void mconv_k(
    const float* __restrict__ src, const float* __restrict__ R,
    const float* __restrict__ S, const _Float16* __restrict__ wp,
    const float* __restrict__ bias, float* __restrict__ out, int job0)
{
    constexpr int PL = 1456;              // 10*18*8 = 1440 + 16 pad (fp16 elems)
    constexpr int Ct = NCT * 16;
    const int jl = blockIdx.y, jg = job0 + jl;
    const int b = jg & 1;
    const int tile = blockIdx.x;          // 8 in x, 16 in y
    const int ty0 = (tile >> 3) << 3, tx0 = (tile & 7) << 4;
    const int tid = threadIdx.x;
    const int lane = tid & 63;
    const int wq = __builtin_amdgcn_readfirstlane(tid >> 6);
    const int n = lane & 15, quad = lane >> 4;

    const float* s0;
    if (SRCMODE == 0)      s0 = src + (size_t)jl * NC * HWP;
    else if (SRCMODE == 1) s0 = R + (size_t)b * NC * HWP;
    else                   s0 = S + (size_t)jl * NC * HWP;

    __shared__ _Float16 hh[8 * PL];
    __shared__ _Float16 ll[8 * PL];

    for (int t = tid; t < 360; t += 256) {
        int px = t >> 1, hf = t & 1;
        int hy = px / 18, hx = px - hy * 18;
        int gy = ty0 - 1 + hy, gx = tx0 - 1 + hx;
        bool ok = (gy >= 0 && gy < HH && gx >= 0 && gx < WW);
        const float* sp = s0 + (ok ? ((size_t)(gy * WW + gx) * 64) : 0) + hf * 32;
        int lb = px * 8;
#pragma unroll
        for (int c = 0; c < 4; ++c) {
            int cb = hf * 4 + c;
            floatx4 f0 = {0.f,0.f,0.f,0.f}, f1 = {0.f,0.f,0.f,0.f};
            if (ok) {
                f0 = *(const floatx4*)(sp + c * 8);
                f1 = *(const floatx4*)(sp + c * 8 + 4);
            }
            union { half8 v; _Float16 e[8]; } ph, pl;
#pragma unroll
            for (int j = 0; j < 4; ++j) {
                _Float16 h0 = (_Float16)f0[j], h1 = (_Float16)f1[j];
                ph.e[j] = h0;     ph.e[j+4] = h1;
                pl.e[j] = (_Float16)(f0[j] - (float)h0);
                pl.e[j+4] = (_Float16)(f1[j] - (float)h1);
            }
            *(half8*)&hh[cb * PL + lb] = ph.v;
            *(half8*)&ll[cb * PL + lb] = pl.v;
        }
    }
    __syncthreads();

    for (int ct = 0; ct < NCT; ++ct) {
        half8 Ah[NKC], Al[NKC];
#pragma unroll
        for (int kc = 0; kc < NKC; ++kc) {
            size_t base = (size_t)((ct * NKC + kc) * 2) * 512;
            Ah[kc] = *(const half8*)(wp + base + lane * 8);
            Al[kc] = *(const half8*)(wp + base + 512 + lane * 8);
        }
        const floatx4 b4 = *(const floatx4*)(bias + ct * 16 + quad * 4);
#pragma unroll
        for (int r = 0; r < 2; ++r) {
            const int y = wq * 2 + r;
            floatx4 acc = {0.f, 0.f, 0.f, 0.f};
#pragma unroll
            for (int kc = 0; kc < NKC; ++kc) {
                const int kk = kc >> 1;
                const int dy = kk / 3, dx = kk % 3;
                const int cb = ((kc & 1) << 2) + quad;
                const int ix = cb * PL + ((y + dy) * 18 + n + dx) * 8;
                half8 Bh = *(const half8*)&hh[ix];
                half8 Bl = *(const half8*)&ll[ix];
                acc = __builtin_amdgcn_mfma_f32_16x16x32_f16(Ah[kc], Bh, acc, 0, 0, 0);
                acc = __builtin_amdgcn_mfma_f32_16x16x32_f16(Ah[kc], Bl, acc, 0, 0, 0);
                acc = __builtin_amdgcn_mfma_f32_16x16x32_f16(Al[kc], Bh, acc, 0, 0, 0);
            }
            const int oy = ty0 + y, ox = tx0 + n;
            float* op = out + ((size_t)jl * HWP + (size_t)oy * WW + ox) * Ct
                            + ct * 16 + quad * 4;
            if (ADD) {
                floatx4 old = *(const floatx4*)op;
                acc += old;
            } else {
                acc += b4;
            }
            *(floatx4*)op = acc;
        }
    }
}

// Deformable conv, MFMA phase B (split-fp16) + low-VGPR phase A. CHANNEL-LAST.
// Block = 8x8 px tile x 4 waves; wave q -> co-tile q (16 co).
// 4 rounds x 2 deform-groups; K padded 144->160/round (pad: zero weights, zeroed samp).
// Phase A: fp32 bilinear, corners in 2 sequential batches (low VGPR), split hi/lo fp16
// into samp_h/samp_l[64][166] (odd dword row stride -> <=2-way banks).
// Phase B: 5 chunks x 4 strips x 3 MFMA per round (Ah*Bh + Ah*Bl + Al*Bh).
__global__ __launch_bounds__(256, 4) void mdeform_k(
    const float* __restrict__ in, const float* __restrict__ off,
    const _Float16* __restrict__ wp, const float* __restrict__ bias,
    float* __restrict__ out, int supp_mode, const float* __restrict__ S)
{
    constexpr int SROW = 166;
    const int jl = blockIdx.y;
    const int tile = blockIdx.x;          // 16x16 tiles of 8x8
    const int ty0 = (tile >> 4) << 3, tx0 = (tile & 15) << 3;
    const int tid = threadIdx.x;
    const int lane = tid & 63;
    const int q = __builtin_amdgcn_readfirstlane(tid >> 6);
    const int n = lane & 15, quad = lane >> 4;

    const float* ibase = supp_mode ? (S + (size_t)jl * NC * HWP)
                                   : (in + (size_t)jl * NC * HWP);
    const float* obase = off + (size_t)jl * OFFC * HWP;

    __shared__ _Float16 sh[64 * SROW];
    __shared__ _Float16 sl[64 * SROW];

    // zero the pad K-slots [144,160) (never written by phase A; MFMA multiplies
    // them by zero weights, but garbage could be NaN -> must be finite/zero)
    for (int e = tid; e < 64 * 16; e += 256) {
        int row = e >> 4, col = 144 + (e & 15);
        sh[row * SROW + col] = (_Float16)0.f;
        sl[row * SROW + col] = (_Float16)0.f;
    }

    floatx4 acc[4];
#pragma unroll
    for (int s = 0; s < 4; ++s) acc[s] = floatx4{0.f, 0.f, 0.f, 0.f};

    for (int r = 0; r < 4; ++r) {
        __syncthreads();
        // ---- phase A: 2 groups x 9 kk x 64 px ----
        for (int tk = tid; tk < 1152; tk += 256) {
            int px = tk & 63;
            int u = tk >> 6;              // wave-uniform 0..17
            int gl = u / 9, kk = u - gl * 9;
            int g = r * 2 + gl;
            int yy = ty0 + (px >> 3), xx = tx0 + (px & 7);
            floatx2 o2 = *(const floatx2*)(obase + (size_t)(yy * WW + xx) * OFFC
                                           + (g * 9 + kk) * 2);
            float pyf = (float)(yy + (kk / 3) - 1) + o2[0];
            float pxf = (float)(xx + (kk % 3) - 1) + o2[1];
            float fy = floorf(pyf), fx = floorf(pxf);
            float wy = pyf - fy, wx = pxf - fx;
            int y0 = (int)fy, x0 = (int)fx;
            int y1 = y0 + 1, x1 = x0 + 1;
            float m00 = (y0 >= 0 && y0 < HH && x0 >= 0 && x0 < WW) ? 1.f : 0.f;
            float m01 = (y0 >= 0 && y0 < HH && x1 >= 0 && x1 < WW) ? 1.f : 0.f;
            float m10 = (y1 >= 0 && y1 < HH && x0 >= 0 && x0 < WW) ? 1.f : 0.f;
            float m11 = (y1 >= 0 && y1 < HH && x1 >= 0 && x1 < WW) ? 1.f : 0.f;
            float w00 = (1.f - wy) * (1.f - wx) * m00;
            float w01 = (1.f - wy) * wx * m01;
            float w10 = wy * (1.f - wx) * m10;
            float w11 = wy * wx * m11;
            int cy0 = min(max(y0, 0), HH - 1), cy1 = min(max(y1, 0), HH - 1);
            int cx0 = min(max(x0, 0), WW - 1), cx1 = min(max(x1, 0), WW - 1);
            const float* p00 = ibase + (size_t)(cy0 * WW + cx0) * 64 + g * 8;
            const float* p01 = ibase + (size_t)(cy0 * WW + cx1) * 64 + g * 8;
            const float* p10 = ibase + (size_t)(cy1 * WW + cx0) * 64 + g * 8;
            const float* p11 = ibase + (size_t)(cy1 * WW + cx1) * 64 + g * 8;
            float s8[8];
            {   // batch 1: top two corners
                floatx4 a0 = *(const floatx4*)p00, a1 = *(const floatx4*)(p00 + 4);
                floatx4 b0 = *(const floatx4*)p01, b1 = *(const floatx4*)(p01 + 4);
#pragma unroll
                for (int j = 0; j < 4; ++j) {
                    s8[j]     = a0[j] * w00 + b0[j] * w01;
                    s8[j + 4] = a1[j] * w00 + b1[j] * w01;
                }
            }
            {   // batch 2: bottom two corners
                floatx4 c0 = *(const floatx4*)p10, c1 = *(const floatx4*)(p10 + 4);
                floatx4 d0 = *(const floatx4*)p11, d1 = *(const floatx4*)(p11 + 4);
#pragma unroll
                for (int j = 0; j < 4; ++j) {
                    s8[j]     += c0[j] * w10 + d0[j] * w11;
                    s8[j + 4] += c1[j] * w10 + d1[j] * w11;
                }
            }
            union { half8 v; _Float16 e[8]; } ph, pl;
#pragma unroll
            for (int j = 0; j < 8; ++j) {
                _Float16 h = (_Float16)s8[j];
                ph.e[j] = h;
                pl.e[j] = (_Float16)(s8[j] - (float)h);
            }
            int sb = px * SROW + gl * 72 + kk * 8;
            *(half8*)&sh[sb] = ph.v;
            *(half8*)&sl[sb] = pl.v;
        }
        __syncthreads();
        // ---- phase B: MFMA contraction, wave q -> co-tile q ----
#pragma unroll
        for (int kc5 = 0; kc5 < 5; ++kc5) {
            int kcg = r * 5 + kc5;
            size_t base = (size_t)((q * 20 + kcg) * 2) * 512;
            half8 Ah = *(const half8*)(wp + base + lane * 8);
            half8 Al = *(const half8*)(wp + base + 512 + lane * 8);
#pragma unroll
            for (int s = 0; s < 4; ++s) {
                int px = s * 16 + n;
                const int ix = px * SROW + kc5 * 32 + quad * 8;
                half8 Bh = *(const half8*)&sh[ix];
                half8 Bl = *(const half8*)&sl[ix];
                acc[s] = __builtin_amdgcn_mfma_f32_16x16x32_f16(Ah, Bh, acc[s], 0, 0, 0);
                acc[s] = __builtin_amdgcn_mfma_f32_16x16x32_f16(Ah, Bl, acc[s], 0, 0, 0);
                acc[s] = __builtin_amdgcn_mfma_f32_16x16x32_f16(Al, Bh, acc[s], 0, 0, 0);
            }
        }
    }
    // epilogue: D(lane,reg i) -> co = q*16 + quad*4 + i, px = strip*16 + n
    const floatx4 b4 = *(const floatx4*)(bias + q * 16 + quad * 4);
#pragma unroll
    for (int s = 0; s < 4; ++s) {
        int px = s * 16 + n;
        int oy = ty0 + (px >> 3), ox = tx0 + (px & 7);
        float* op = out + ((size_t)jl * HWP + (size_t)oy * WW + ox) * 64
                        + q * 16 + quad * 4;
        *(floatx4*)op = acc[s] + b4;
    }
}

// rec conv (64 -> 3): fp32, channel-last input. Writes d_out (planar).
__global__ __launch_bounds__(256) void conv3x3_rec_k(
    const float* __restrict__ in, const float* __restrict__ w,
    const float* __restrict__ bias, float* __restrict__ out, int job0)
{
    constexpr int CB = 8;
    constexpr int PITCH = 48;
    constexpr int CH = 18 * PITCH;
    const int jl = blockIdx.y, jg = job0 + jl;
    const int b = jg & 1, fi = jg >> 1;
    const int frame = fi + (fi >= 2 ? 1 : 0);
    const int tile = blockIdx.x;
    const int ty0 = (tile >> 3) << 4, tx0 = (tile & 7) << 4;
    const int tid = threadIdx.x;
    const int tx = tid & 15, ty = tid >> 4;
    const float* srcA = in + (size_t)jl * NC * HWP;

    __shared__ float lds[CB * CH];
    float acc[3] = {bias[0], bias[1], bias[2]};

    for (int cb = 0; cb < NC; cb += CB) {
        __syncthreads();
        for (int e = tid; e < CB * 324; e += 256) {
            int c = e & 7;
            int r = e >> 3;
            int iy = r / 18, ix = r - iy * 18;
            int gy = ty0 - 1 + iy, gx = tx0 - 1 + ix;
            float v = 0.f;
            if (gy >= 0 && gy < HH && gx >= 0 && gx < WW)
                v = srcA[(size_t)(gy * WW + gx) * 64 + cb + c];
            lds[c * CH + iy * PITCH + ix] = v;
        }
        __syncthreads();
#pragma unroll
        for (int c = 0; c < CB; ++c) {
            float t[9];
#pragma unroll
            for (int dy = 0; dy < 3; ++dy)
#pragma unroll
                for (int dx = 0; dx < 3; ++dx)
                    t[dy * 3 + dx] = lds[c * CH + (ty + dy) * PITCH + (tx + dx)];
            int ci = cb + c;
#pragma unroll
            for (int o = 0; o < 3; ++o) {
                const float* wo = w + ((size_t)o * NC + ci) * 9;
#pragma unroll
                for (int kk = 0; kk < 9; ++kk)
                    acc[o] = fmaf(wo[kk], t[kk], acc[o]);
            }
        }
    }
    const int oy = ty0 + ty, ox = tx0 + tx;
#pragma unroll
    for (int o = 0; o < 3; ++o)
        out[((size_t)(b * NN + frame) * 3 + o) * HWP + oy * WW + ox] = acc[o];
}

extern "C" void kernel_launch(void* const* d_in, const int* in_sizes, int n_in,
                              void* d_out, int out_size, void* d_ws, size_t ws_size,
                              hipStream_t stream)
{
    const float* pf    = (const float*)d_in[0];
    const float* xc    = (const float*)d_in[1];
    const float* cr_w  = (const float*)d_in[2];
    const float* cr_b  = (const float*)d_in[3];
    const float* ow[4] = {(const float*)d_in[4],  (const float*)d_in[8],
                          (const float*)d_in[12], (const float*)d_in[16]};
    const float* ob[4] = {(const float*)d_in[5],  (const float*)d_in[9],
                          (const float*)d_in[13], (const float*)d_in[17]};
    const float* dw[4] = {(const float*)d_in[6],  (const float*)d_in[10],
                          (const float*)d_in[14], (const float*)d_in[18]};
    const float* db[4] = {(const float*)d_in[7],  (const float*)d_in[11],
                          (const float*)d_in[15], (const float*)d_in[19]};
    const float* rec_w = (const float*)d_in[20];
    const float* rec_b = (const float*)d_in[21];
    float* out = (float*)d_out;

    // ws layout: [wp cr x2][wp of x4][wp dc x4][R 2][S JC][A JC][Bb JC][O JC]
    const size_t WPC = (size_t)4 * NKC * 1024;     // conv 4 co-tiles, 18 chunks
    const size_t WPO = (size_t)9 * NKC * 1024;     // conv 9 co-tiles
    const size_t WPD = (size_t)4 * 20 * 1024;      // deform 4 co-tiles, 20 chunks
    _Float16* wp_cr0 = (_Float16*)d_ws;
    _Float16* wp_cr1 = wp_cr0 + WPC;
    _Float16* wp_of[4];
    _Float16* wp_dc[4];
    _Float16* curh = wp_cr1 + WPC;
    for (int i = 0; i < 4; ++i) { wp_of[i] = curh; curh += WPO; }
    for (int i = 0; i < 4; ++i) { wp_dc[i] = curh; curh += WPD; }
    size_t wp_bytes = (size_t)((char*)curh - (char*)d_ws);

    const size_t fplane = (size_t)NC * HWP;            // floats
    const size_t oplane = (size_t)OFFC * HWP;
    int JC = 8;
    while (JC > 1 &&
           wp_bytes + (2 + 3 * (size_t)JC) * fplane * 4 + (size_t)JC * oplane * 4 > ws_size)
        JC >>= 1;
    float* R  = (float*)curh;
    float* S  = R  + 2 * fplane;
    float* A  = S  + (size_t)JC * fplane;
    float* Bb = A  + (size_t)JC * fplane;
    float* O  = Bb + (size_t)JC * fplane;

    // ---- weight preprocessing + ref repack (every call; ws re-poisoned) ----
    {
        int nc4 = 4 * NKC * 64, nc9 = 9 * NKC * 64, ncd = 4 * 20 * 64;
        dim3 b4((nc4 + 255) / 256), b9((nc9 + 255) / 256), bd((ncd + 255) / 256);
        prew_k<<<b4, 256, 0, stream>>>(cr_w, wp_cr0, 4, NKC, 0, 0, 128);
        prew_k<<<b4, 256, 0, stream>>>(cr_w, wp_cr1, 4, NKC, 0, 64, 128);
        for (int i = 0; i < 4; ++i) {
            prew_k<<<b9, 256, 0, stream>>>(ow[i], wp_of[i], 9, NKC, 0, 0, 64);
            prew_k<<<bd, 256, 0, stream>>>(dw[i], wp_dc[i], 4, 20, 1, 0, 64);
        }
        repack_k<<<dim3(256, 2), 256, 0, stream>>>(pf, R, 0, 1);
    }

    copy_center_k<<<dim3((NB * 3 * HWP + 255) / 256), 256, 0, stream>>>(xc, out);

    for (int job0 = 0; job0 < 8; job0 += JC) {
        dim3 blk(256);
        dim3 gconv(128, JC), gdef(256, JC), grec(64, JC);
        repack_k<<<dim3(256, JC), blk, 0, stream>>>(pf, S, job0, 0);
        // fea1 = cr_conv(concat(ref, supp)) : two K=576 passes (ref, then supp ADD)
        mconv_k<4, 1, 0><<<gconv, blk, 0, stream>>>(nullptr, R, S, wp_cr0, cr_b, A, job0);
        mconv_k<4, 2, 1><<<gconv, blk, 0, stream>>>(nullptr, R, S, wp_cr1, cr_b, A, job0);
        // off1(fea1); fea2 = deform(fea1)
        mconv_k<9, 0, 0><<<gconv, blk, 0, stream>>>(A, R, S, wp_of[0], ob[0], O, job0);
        mdeform_k<<<gdef, blk, 0, stream>>>(A, O, wp_dc[0], db[0], Bb, 0, S);
        // off2(fea2); fea3 = deform(fea2)
        mconv_k<9, 0, 0><<<gconv, blk, 0, stream>>>(Bb, R, S, wp_of[1], ob[1], O, job0);
        mdeform_k<<<gdef, blk, 0, stream>>>(Bb, O, wp_dc[1], db[1], A, 0, S);
        // off3(fea3); fea4 = deform(supp)
        mconv_k<9, 0, 0><<<gconv, blk, 0, stream>>>(A, R, S, wp_of[2], ob[2], O, job0);
        mdeform_k<<<gdef, blk, 0, stream>>>(nullptr, O, wp_dc[2], db[2], Bb, 1, S);
        // off4(fea4); aligned = deform(fea4)
        mconv_k<9, 0, 0><<<gconv, blk, 0, stream>>>(Bb, R, S, wp_of[3], ob[3], O, job0);
        mdeform_k<<<gdef, blk, 0, stream>>>(Bb, O, wp_dc[3], db[3], A, 0, S);
        // out[b, frame] = rec_conv(aligned)
        conv3x3_rec_k<<<grec, blk, 0, stream>>>(A, rec_w, rec_b, out, job0);
    }
}

// Round 11
// 1485.558 us; speedup vs baseline: 2.5135x; 1.2122x over previous
//
#include <hip/hip_runtime.h>

#define HH 128
#define WW 128
#define HWP (HH*WW)
#define NC 64
#define NB 2
#define NN 5
#define OFFC 144
#define NKC 18                    // K-chunks of 32 per 576-K conv pass

typedef __attribute__((ext_vector_type(8))) _Float16 half8;
typedef __attribute__((ext_vector_type(4))) float floatx4;
typedef __attribute__((ext_vector_type(2))) float floatx2;

// out[b, center=2] = x_center
__global__ __launch_bounds__(256) void copy_center_k(const float* __restrict__ xc,
                                                     float* __restrict__ out) {
    int idx = blockIdx.x * 256 + threadIdx.x;
    const int total = NB * 3 * HWP;
    if (idx >= total) return;
    int b = idx / (3 * HWP);
    int r = idx - b * 3 * HWP;
    out[(size_t)((b * NN + 2) * 3) * HWP + r] = xc[idx];
}

// Repack planar pf frame -> channel-last [px][64]. is_ref: blockIdx.y = b (center frame);
// else blockIdx.y = jl (supp frame of job job0+jl). LDS 64x65 transpose tile.
__global__ __launch_bounds__(256) void repack_k(const float* __restrict__ pf,
                                                float* __restrict__ dst, int job0, int is_ref)
{
    __shared__ float T[64][65];
    const int jl = blockIdx.y;
    const float* src;
    if (is_ref) {
        src = pf + (size_t)((jl * NN + 2) * NC) * HWP;
    } else {
        int jg = job0 + jl;
        int b = jg & 1, fi = jg >> 1;
        int frame = fi + (fi >= 2 ? 1 : 0);
        src = pf + (size_t)((b * NN + frame) * NC) * HWP;
    }
    float* d = dst + (size_t)jl * NC * HWP;
    const int p0 = blockIdx.x * 64;
    const int tid = threadIdx.x;
    const int lx = tid & 63, cg4 = tid >> 6;
#pragma unroll
    for (int cc = 0; cc < 16; ++cc) {
        int c = cc * 4 + cg4;
        T[c][lx] = src[(size_t)c * HWP + p0 + lx];
    }
    __syncthreads();
    const int px = tid >> 2, c0 = (tid & 3) * 16;
#pragma unroll
    for (int j = 0; j < 4; ++j) {
        floatx4 v = { T[c0 + j*4 + 0][px], T[c0 + j*4 + 1][px],
                      T[c0 + j*4 + 2][px], T[c0 + j*4 + 3][px] };
        *(floatx4*)(d + (size_t)(p0 + px) * 64 + c0 + j*4) = v;
    }
}

// Weight preprocessor, SPLIT-fp16: w[co][cin_src][9] -> wp[ct][kc][{hi,lo}][lane][8],
// k = kc*32 + (lane>>4)*8 + j.
// mode 0 (conv, nkc=18):   kk = k>>6, ci = k&63 (+ci_off).
// mode 1 (deform, nkc=20): r = k/160, kr = k%160; kr<144: g = r*2 + kr/72,
//                          kk = (kr%72)>>3, cg = kr&7, ci = g*8+cg; else zero pad.
__global__ __launch_bounds__(256) void prew_k(const float* __restrict__ w,
                                              _Float16* __restrict__ wp,
                                              int nct, int nkc, int mode,
                                              int ci_off, int cin_src)
{
    int idx = blockIdx.x * 256 + threadIdx.x;
    if (idx >= nct * nkc * 64) return;
    int lane = idx & 63;
    int kc = (idx >> 6) % nkc;
    int ct = (idx >> 6) / nkc;
    int m = lane & 15, quad = lane >> 4;
    int co = ct * 16 + m;
    union { half8 v; _Float16 e[8]; } ph, pl;
#pragma unroll
    for (int j = 0; j < 8; ++j) {
        int k = kc * 32 + quad * 8 + j;
        float f = 0.f;
        if (mode == 0) {
            int kk = k >> 6, ci = k & 63;
            f = w[((size_t)co * cin_src + ci_off + ci) * 9 + kk];
        } else {
            int r = k / 160, kr = k - r * 160;
            if (kr < 144) {
                int g = r * 2 + kr / 72;
                int rr = kr % 72;
                int kk = rr >> 3, cg = rr & 7;
                f = w[((size_t)co * cin_src + g * 8 + cg) * 9 + kk];
            }
        }
        _Float16 h = (_Float16)f;
        ph.e[j] = h; pl.e[j] = (_Float16)(f - (float)h);
    }
    size_t base = (size_t)((ct * nkc + kc) * 2) * 512;
    *(half8*)(wp + base + lane * 8) = ph.v;
    *(half8*)(wp + base + 512 + lane * 8) = pl.v;
}

// SPLIT-fp16 MFMA 3x3 conv, CHANNEL-LAST src & dst.
// R11: K-loop INVERTED (kc outer, ct inner). Per kc the wave's two B-rows are read
// once from LDS (4 ds_read_b128, reused across all NCT co-tiles -> 9x fewer LDS
// reads), A-frags streamed just-in-time from wp (8 VGPR live, no 144-reg array ->
// no spills; R10 had VGPR_Count=128 < 144-reg A-array -> scratch traffic).
// Accumulators acc0/acc1[NCT] (72 VGPR at NCT=9).
template<int NCT, int SRCMODE, int ADD>
__global__ __launch_bounds__(256, 3) void mconv_k(
    const float* __restrict__ src, const float* __restrict__ R,
    const float* __restrict__ S, const _Float16* __restrict__ wp,
    const float* __restrict__ bias, float* __restrict__ out, int job0)
{
    constexpr int PL = 1456;              // 10*18*8 = 1440 + 16 pad (fp16 elems)
    constexpr int Ct = NCT * 16;
    const int jl = blockIdx.y, jg = job0 + jl;
    const int b = jg & 1;
    const int tile = blockIdx.x;          // 8 in x, 16 in y
    const int ty0 = (tile >> 3) << 3, tx0 = (tile & 7) << 4;
    const int tid = threadIdx.x;
    const int lane = tid & 63;
    const int wq = __builtin_amdgcn_readfirstlane(tid >> 6);
    const int n = lane & 15, quad = lane >> 4;

    const float* s0;
    if (SRCMODE == 0)      s0 = src + (size_t)jl * NC * HWP;
    else if (SRCMODE == 1) s0 = R + (size_t)b * NC * HWP;
    else                   s0 = S + (size_t)jl * NC * HWP;

    __shared__ _Float16 hh[8 * PL];
    __shared__ _Float16 ll[8 * PL];

    // ---- stage halo (180 px x 64 ci), channel-last coalesced float4 reads ----
    for (int t = tid; t < 360; t += 256) {
        int px = t >> 1, hf = t & 1;
        int hy = px / 18, hx = px - hy * 18;
        int gy = ty0 - 1 + hy, gx = tx0 - 1 + hx;
        bool ok = (gy >= 0 && gy < HH && gx >= 0 && gx < WW);
        const float* sp = s0 + (ok ? ((size_t)(gy * WW + gx) * 64) : 0) + hf * 32;
        int lb = px * 8;
#pragma unroll
        for (int c = 0; c < 4; ++c) {
            int cb = hf * 4 + c;
            floatx4 f0 = {0.f,0.f,0.f,0.f}, f1 = {0.f,0.f,0.f,0.f};
            if (ok) {
                f0 = *(const floatx4*)(sp + c * 8);
                f1 = *(const floatx4*)(sp + c * 8 + 4);
            }
            union { half8 v; _Float16 e[8]; } ph, pl;
#pragma unroll
            for (int j = 0; j < 4; ++j) {
                _Float16 h0 = (_Float16)f0[j], h1 = (_Float16)f1[j];
                ph.e[j] = h0;     ph.e[j+4] = h1;
                pl.e[j] = (_Float16)(f0[j] - (float)h0);
                pl.e[j+4] = (_Float16)(f1[j] - (float)h1);
            }
            *(half8*)&hh[cb * PL + lb] = ph.v;
            *(half8*)&ll[cb * PL + lb] = pl.v;
        }
    }
    __syncthreads();

    // ---- compute: kc outer, ct inner ----
    floatx4 acc0[NCT], acc1[NCT];
#pragma unroll
    for (int ct = 0; ct < NCT; ++ct) {
        acc0[ct] = floatx4{0.f, 0.f, 0.f, 0.f};
        acc1[ct] = floatx4{0.f, 0.f, 0.f, 0.f};
    }
    const int y0 = wq * 2, y1 = y0 + 1;
#pragma unroll
    for (int kc = 0; kc < NKC; ++kc) {
        const int kk = kc >> 1;
        const int dy = kk / 3, dx = kk % 3;
        const int cb = ((kc & 1) << 2) + quad;
        const int ix0 = cb * PL + ((y0 + dy) * 18 + n + dx) * 8;
        const int ix1 = cb * PL + ((y1 + dy) * 18 + n + dx) * 8;
        half8 B0h = *(const half8*)&hh[ix0];
        half8 B0l = *(const half8*)&ll[ix0];
        half8 B1h = *(const half8*)&hh[ix1];
        half8 B1l = *(const half8*)&ll[ix1];
        const _Float16* wk = wp + (size_t)kc * 1024 + lane * 8;
#pragma unroll
        for (int ct = 0; ct < NCT; ++ct) {
            const _Float16* wc = wk + (size_t)ct * NKC * 1024;
            half8 Ah = *(const half8*)wc;
            half8 Al = *(const half8*)(wc + 512);
            acc0[ct] = __builtin_amdgcn_mfma_f32_16x16x32_f16(Ah, B0h, acc0[ct], 0, 0, 0);
            acc0[ct] = __builtin_amdgcn_mfma_f32_16x16x32_f16(Ah, B0l, acc0[ct], 0, 0, 0);
            acc0[ct] = __builtin_amdgcn_mfma_f32_16x16x32_f16(Al, B0h, acc0[ct], 0, 0, 0);
            acc1[ct] = __builtin_amdgcn_mfma_f32_16x16x32_f16(Ah, B1h, acc1[ct], 0, 0, 0);
            acc1[ct] = __builtin_amdgcn_mfma_f32_16x16x32_f16(Ah, B1l, acc1[ct], 0, 0, 0);
            acc1[ct] = __builtin_amdgcn_mfma_f32_16x16x32_f16(Al, B1h, acc1[ct], 0, 0, 0);
        }
    }

    // ---- epilogue ----
    const int oy0 = ty0 + y0, oy1 = ty0 + y1, ox = tx0 + n;
#pragma unroll
    for (int ct = 0; ct < NCT; ++ct) {
        const floatx4 b4 = *(const floatx4*)(bias + ct * 16 + quad * 4);
        float* op0 = out + ((size_t)jl * HWP + (size_t)oy0 * WW + ox) * Ct
                         + ct * 16 + quad * 4;
        float* op1 = out + ((size_t)jl * HWP + (size_t)oy1 * WW + ox) * Ct
                         + ct * 16 + quad * 4;
        floatx4 v0 = acc0[ct], v1 = acc1[ct];
        if (ADD) {
            v0 += *(const floatx4*)op0;
            v1 += *(const floatx4*)op1;
        } else {
            v0 += b4;
            v1 += b4;
        }
        *(floatx4*)op0 = v0;
        *(floatx4*)op1 = v1;
    }
}

// Deformable conv, MFMA phase B (split-fp16) + low-VGPR phase A. CHANNEL-LAST.
// Unchanged from R10 (proven).
__global__ __launch_bounds__(256, 4) void mdeform_k(
    const float* __restrict__ in, const float* __restrict__ off,
    const _Float16* __restrict__ wp, const float* __restrict__ bias,
    float* __restrict__ out, int supp_mode, const float* __restrict__ S)
{
    constexpr int SROW = 166;
    const int jl = blockIdx.y;
    const int tile = blockIdx.x;          // 16x16 tiles of 8x8
    const int ty0 = (tile >> 4) << 3, tx0 = (tile & 15) << 3;
    const int tid = threadIdx.x;
    const int lane = tid & 63;
    const int q = __builtin_amdgcn_readfirstlane(tid >> 6);
    const int n = lane & 15, quad = lane >> 4;

    const float* ibase = supp_mode ? (S + (size_t)jl * NC * HWP)
                                   : (in + (size_t)jl * NC * HWP);
    const float* obase = off + (size_t)jl * OFFC * HWP;

    __shared__ _Float16 sh[64 * SROW];
    __shared__ _Float16 sl[64 * SROW];

    for (int e = tid; e < 64 * 16; e += 256) {
        int row = e >> 4, col = 144 + (e & 15);
        sh[row * SROW + col] = (_Float16)0.f;
        sl[row * SROW + col] = (_Float16)0.f;
    }

    floatx4 acc[4];
#pragma unroll
    for (int s = 0; s < 4; ++s) acc[s] = floatx4{0.f, 0.f, 0.f, 0.f};

    for (int r = 0; r < 4; ++r) {
        __syncthreads();
        for (int tk = tid; tk < 1152; tk += 256) {
            int px = tk & 63;
            int u = tk >> 6;
            int gl = u / 9, kk = u - gl * 9;
            int g = r * 2 + gl;
            int yy = ty0 + (px >> 3), xx = tx0 + (px & 7);
            floatx2 o2 = *(const floatx2*)(obase + (size_t)(yy * WW + xx) * OFFC
                                           + (g * 9 + kk) * 2);
            float pyf = (float)(yy + (kk / 3) - 1) + o2[0];
            float pxf = (float)(xx + (kk % 3) - 1) + o2[1];
            float fy = floorf(pyf), fx = floorf(pxf);
            float wy = pyf - fy, wx = pxf - fx;
            int y0 = (int)fy, x0 = (int)fx;
            int y1 = y0 + 1, x1 = x0 + 1;
            float m00 = (y0 >= 0 && y0 < HH && x0 >= 0 && x0 < WW) ? 1.f : 0.f;
            float m01 = (y0 >= 0 && y0 < HH && x1 >= 0 && x1 < WW) ? 1.f : 0.f;
            float m10 = (y1 >= 0 && y1 < HH && x0 >= 0 && x0 < WW) ? 1.f : 0.f;
            float m11 = (y1 >= 0 && y1 < HH && x1 >= 0 && x1 < WW) ? 1.f : 0.f;
            float w00 = (1.f - wy) * (1.f - wx) * m00;
            float w01 = (1.f - wy) * wx * m01;
            float w10 = wy * (1.f - wx) * m10;
            float w11 = wy * wx * m11;
            int cy0 = min(max(y0, 0), HH - 1), cy1 = min(max(y1, 0), HH - 1);
            int cx0 = min(max(x0, 0), WW - 1), cx1 = min(max(x1, 0), WW - 1);
            const float* p00 = ibase + (size_t)(cy0 * WW + cx0) * 64 + g * 8;
            const float* p01 = ibase + (size_t)(cy0 * WW + cx1) * 64 + g * 8;
            const float* p10 = ibase + (size_t)(cy1 * WW + cx0) * 64 + g * 8;
            const float* p11 = ibase + (size_t)(cy1 * WW + cx1) * 64 + g * 8;
            float s8[8];
            {
                floatx4 a0 = *(const floatx4*)p00, a1 = *(const floatx4*)(p00 + 4);
                floatx4 b0 = *(const floatx4*)p01, b1 = *(const floatx4*)(p01 + 4);
#pragma unroll
                for (int j = 0; j < 4; ++j) {
                    s8[j]     = a0[j] * w00 + b0[j] * w01;
                    s8[j + 4] = a1[j] * w00 + b1[j] * w01;
                }
            }
            {
                floatx4 c0 = *(const floatx4*)p10, c1 = *(const floatx4*)(p10 + 4);
                floatx4 d0 = *(const floatx4*)p11, d1 = *(const floatx4*)(p11 + 4);
#pragma unroll
                for (int j = 0; j < 4; ++j) {
                    s8[j]     += c0[j] * w10 + d0[j] * w11;
                    s8[j + 4] += c1[j] * w10 + d1[j] * w11;
                }
            }
            union { half8 v; _Float16 e[8]; } ph, pl;
#pragma unroll
            for (int j = 0; j < 8; ++j) {
                _Float16 h = (_Float16)s8[j];
                ph.e[j] = h;
                pl.e[j] = (_Float16)(s8[j] - (float)h);
            }
            int sb = px * SROW + gl * 72 + kk * 8;
            *(half8*)&sh[sb] = ph.v;
            *(half8*)&sl[sb] = pl.v;
        }
        __syncthreads();
#pragma unroll
        for (int kc5 = 0; kc5 < 5; ++kc5) {
            int kcg = r * 5 + kc5;
            size_t base = (size_t)((q * 20 + kcg) * 2) * 512;
            half8 Ah = *(const half8*)(wp + base + lane * 8);
            half8 Al = *(const half8*)(wp + base + 512 + lane * 8);
#pragma unroll
            for (int s = 0; s < 4; ++s) {
                int px = s * 16 + n;
                const int ix = px * SROW + kc5 * 32 + quad * 8;
                half8 Bh = *(const half8*)&sh[ix];
                half8 Bl = *(const half8*)&sl[ix];
                acc[s] = __builtin_amdgcn_mfma_f32_16x16x32_f16(Ah, Bh, acc[s], 0, 0, 0);
                acc[s] = __builtin_amdgcn_mfma_f32_16x16x32_f16(Ah, Bl, acc[s], 0, 0, 0);
                acc[s] = __builtin_amdgcn_mfma_f32_16x16x32_f16(Al, Bh, acc[s], 0, 0, 0);
            }
        }
    }
    const floatx4 b4 = *(const floatx4*)(bias + q * 16 + quad * 4);
#pragma unroll
    for (int s = 0; s < 4; ++s) {
        int px = s * 16 + n;
        int oy = ty0 + (px >> 3), ox = tx0 + (px & 7);
        float* op = out + ((size_t)jl * HWP + (size_t)oy * WW + ox) * 64
                        + q * 16 + quad * 4;
        *(floatx4*)op = acc[s] + b4;
    }
}

// rec conv (64 -> 3): fp32, channel-last input. Writes d_out (planar).
__global__ __launch_bounds__(256) void conv3x3_rec_k(
    const float* __restrict__ in, const float* __restrict__ w,
    const float* __restrict__ bias, float* __restrict__ out, int job0)
{
    constexpr int CB = 8;
    constexpr int PITCH = 48;
    constexpr int CH = 18 * PITCH;
    const int jl = blockIdx.y, jg = job0 + jl;
    const int b = jg & 1, fi = jg >> 1;
    const int frame = fi + (fi >= 2 ? 1 : 0);
    const int tile = blockIdx.x;
    const int ty0 = (tile >> 3) << 4, tx0 = (tile & 7) << 4;
    const int tid = threadIdx.x;
    const int tx = tid & 15, ty = tid >> 4;
    const float* srcA = in + (size_t)jl * NC * HWP;

    __shared__ float lds[CB * CH];
    float acc[3] = {bias[0], bias[1], bias[2]};

    for (int cb = 0; cb < NC; cb += CB) {
        __syncthreads();
        for (int e = tid; e < CB * 324; e += 256) {
            int c = e & 7;
            int r = e >> 3;
            int iy = r / 18, ix = r - iy * 18;
            int gy = ty0 - 1 + iy, gx = tx0 - 1 + ix;
            float v = 0.f;
            if (gy >= 0 && gy < HH && gx >= 0 && gx < WW)
                v = srcA[(size_t)(gy * WW + gx) * 64 + cb + c];
            lds[c * CH + iy * PITCH + ix] = v;
        }
        __syncthreads();
#pragma unroll
        for (int c = 0; c < CB; ++c) {
            float t[9];
#pragma unroll
            for (int dy = 0; dy < 3; ++dy)
#pragma unroll
                for (int dx = 0; dx < 3; ++dx)
                    t[dy * 3 + dx] = lds[c * CH + (ty + dy) * PITCH + (tx + dx)];
            int ci = cb + c;
#pragma unroll
            for (int o = 0; o < 3; ++o) {
                const float* wo = w + ((size_t)o * NC + ci) * 9;
#pragma unroll
                for (int kk = 0; kk < 9; ++kk)
                    acc[o] = fmaf(wo[kk], t[kk], acc[o]);
            }
        }
    }
    const int oy = ty0 + ty, ox = tx0 + tx;
#pragma unroll
    for (int o = 0; o < 3; ++o)
        out[((size_t)(b * NN + frame) * 3 + o) * HWP + oy * WW + ox] = acc[o];
}

extern "C" void kernel_launch(void* const* d_in, const int* in_sizes, int n_in,
                              void* d_out, int out_size, void* d_ws, size_t ws_size,
                              hipStream_t stream)
{
    const float* pf    = (const float*)d_in[0];
    const float* xc    = (const float*)d_in[1];
    const float* cr_w  = (const float*)d_in[2];
    const float* cr_b  = (const float*)d_in[3];
    const float* ow[4] = {(const float*)d_in[4],  (const float*)d_in[8],
                          (const float*)d_in[12], (const float*)d_in[16]};
    const float* ob[4] = {(const float*)d_in[5],  (const float*)d_in[9],
                          (const float*)d_in[13], (const float*)d_in[17]};
    const float* dw[4] = {(const float*)d_in[6],  (const float*)d_in[10],
                          (const float*)d_in[14], (const float*)d_in[18]};
    const float* db[4] = {(const float*)d_in[7],  (const float*)d_in[11],
                          (const float*)d_in[15], (const float*)d_in[19]};
    const float* rec_w = (const float*)d_in[20];
    const float* rec_b = (const float*)d_in[21];
    float* out = (float*)d_out;

    // ws layout: [wp cr x2][wp of x4][wp dc x4][R 2][S JC][A JC][Bb JC][O JC]
    const size_t WPC = (size_t)4 * NKC * 1024;
    const size_t WPO = (size_t)9 * NKC * 1024;
    const size_t WPD = (size_t)4 * 20 * 1024;
    _Float16* wp_cr0 = (_Float16*)d_ws;
    _Float16* wp_cr1 = wp_cr0 + WPC;
    _Float16* wp_of[4];
    _Float16* wp_dc[4];
    _Float16* curh = wp_cr1 + WPC;
    for (int i = 0; i < 4; ++i) { wp_of[i] = curh; curh += WPO; }
    for (int i = 0; i < 4; ++i) { wp_dc[i] = curh; curh += WPD; }
    size_t wp_bytes = (size_t)((char*)curh - (char*)d_ws);

    const size_t fplane = (size_t)NC * HWP;
    const size_t oplane = (size_t)OFFC * HWP;
    int JC = 8;
    while (JC > 1 &&
           wp_bytes + (2 + 3 * (size_t)JC) * fplane * 4 + (size_t)JC * oplane * 4 > ws_size)
        JC >>= 1;
    float* R  = (float*)curh;
    float* S  = R  + 2 * fplane;
    float* A  = S  + (size_t)JC * fplane;
    float* Bb = A  + (size_t)JC * fplane;
    float* O  = Bb + (size_t)JC * fplane;

    // ---- weight preprocessing + ref repack (every call; ws re-poisoned) ----
    {
        int nc4 = 4 * NKC * 64, nc9 = 9 * NKC * 64, ncd = 4 * 20 * 64;
        dim3 b4((nc4 + 255) / 256), b9((nc9 + 255) / 256), bd((ncd + 255) / 256);
        prew_k<<<b4, 256, 0, stream>>>(cr_w, wp_cr0, 4, NKC, 0, 0, 128);
        prew_k<<<b4, 256, 0, stream>>>(cr_w, wp_cr1, 4, NKC, 0, 64, 128);
        for (int i = 0; i < 4; ++i) {
            prew_k<<<b9, 256, 0, stream>>>(ow[i], wp_of[i], 9, NKC, 0, 0, 64);
            prew_k<<<bd, 256, 0, stream>>>(dw[i], wp_dc[i], 4, 20, 1, 0, 64);
        }
        repack_k<<<dim3(256, 2), 256, 0, stream>>>(pf, R, 0, 1);
    }

    copy_center_k<<<dim3((NB * 3 * HWP + 255) / 256), 256, 0, stream>>>(xc, out);

    for (int job0 = 0; job0 < 8; job0 += JC) {
        dim3 blk(256);
        dim3 gconv(128, JC), gdef(256, JC), grec(64, JC);
        repack_k<<<dim3(256, JC), blk, 0, stream>>>(pf, S, job0, 0);
        // fea1 = cr_conv(concat(ref, supp)) : two K=576 passes (ref, then supp ADD)
        mconv_k<4, 1, 0><<<gconv, blk, 0, stream>>>(nullptr, R, S, wp_cr0, cr_b, A, job0);
        mconv_k<4, 2, 1><<<gconv, blk, 0, stream>>>(nullptr, R, S, wp_cr1, cr_b, A, job0);
        // off1(fea1); fea2 = deform(fea1)
        mconv_k<9, 0, 0><<<gconv, blk, 0, stream>>>(A, R, S, wp_of[0], ob[0], O, job0);
        mdeform_k<<<gdef, blk, 0, stream>>>(A, O, wp_dc[0], db[0], Bb, 0, S);
        // off2(fea2); fea3 = deform(fea2)
        mconv_k<9, 0, 0><<<gconv, blk, 0, stream>>>(Bb, R, S, wp_of[1], ob[1], O, job0);
        mdeform_k<<<gdef, blk, 0, stream>>>(Bb, O, wp_dc[1], db[1], A, 0, S);
        // off3(fea3); fea4 = deform(supp)
        mconv_k<9, 0, 0><<<gconv, blk, 0, stream>>>(A, R, S, wp_of[2], ob[2], O, job0);
        mdeform_k<<<gdef, blk, 0, stream>>>(nullptr, O, wp_dc[2], db[2], Bb, 1, S);
        // off4(fea4); aligned = deform(fea4)
        mconv_k<9, 0, 0><<<gconv, blk, 0, stream>>>(Bb, R, S, wp_of[3], ob[3], O, job0);
        mdeform_k<<<gdef, blk, 0, stream>>>(Bb, O, wp_dc[3], db[3], A, 0, S);
        // out[b, frame] = rec_conv(aligned)
        conv3x3_rec_k<<<grec, blk, 0, stream>>>(A, rec_w, rec_b, out, job0);
    }
}

// Round 12
// 1326.192 us; speedup vs baseline: 2.8156x; 1.1202x over previous
//
#include <hip/hip_runtime.h>

#define HH 128
#define WW 128
#define HWP (HH*WW)
#define NC 64
#define NB 2
#define NN 5
#define OFFC 144
#define NKC 18                    // K-chunks of 32 per 576-K conv pass

typedef __attribute__((ext_vector_type(8))) _Float16 half8;
typedef __attribute__((ext_vector_type(4))) float floatx4;
typedef __attribute__((ext_vector_type(2))) float floatx2;

// out[b, center=2] = x_center
__global__ __launch_bounds__(256) void copy_center_k(const float* __restrict__ xc,
                                                     float* __restrict__ out) {
    int idx = blockIdx.x * 256 + threadIdx.x;
    const int total = NB * 3 * HWP;
    if (idx >= total) return;
    int b = idx / (3 * HWP);
    int r = idx - b * 3 * HWP;
    out[(size_t)((b * NN + 2) * 3) * HWP + r] = xc[idx];
}

// Repack planar pf frame -> channel-last [px][64]. is_ref: blockIdx.y = b (center frame);
// else blockIdx.y = jl (supp frame of job job0+jl). LDS 64x65 transpose tile.
__global__ __launch_bounds__(256) void repack_k(const float* __restrict__ pf,
                                                float* __restrict__ dst, int job0, int is_ref)
{
    __shared__ float T[64][65];
    const int jl = blockIdx.y;
    const float* src;
    if (is_ref) {
        src = pf + (size_t)((jl * NN + 2) * NC) * HWP;
    } else {
        int jg = job0 + jl;
        int b = jg & 1, fi = jg >> 1;
        int frame = fi + (fi >= 2 ? 1 : 0);
        src = pf + (size_t)((b * NN + frame) * NC) * HWP;
    }
    float* d = dst + (size_t)jl * NC * HWP;
    const int p0 = blockIdx.x * 64;
    const int tid = threadIdx.x;
    const int lx = tid & 63, cg4 = tid >> 6;
#pragma unroll
    for (int cc = 0; cc < 16; ++cc) {
        int c = cc * 4 + cg4;
        T[c][lx] = src[(size_t)c * HWP + p0 + lx];
    }
    __syncthreads();
    const int px = tid >> 2, c0 = (tid & 3) * 16;
#pragma unroll
    for (int j = 0; j < 4; ++j) {
        floatx4 v = { T[c0 + j*4 + 0][px], T[c0 + j*4 + 1][px],
                      T[c0 + j*4 + 2][px], T[c0 + j*4 + 3][px] };
        *(floatx4*)(d + (size_t)(p0 + px) * 64 + c0 + j*4) = v;
    }
}

// Weight preprocessor, SPLIT-fp16: w[co][cin_src][9] -> wp[ct][kc][{hi,lo}][lane][8],
// k = kc*32 + (lane>>4)*8 + j.
// mode 0 (conv, nkc=18):   kk = k>>6, ci = k&63 (+ci_off).
// mode 1 (deform, nkc=20): r = k/160, kr = k%160; kr<144: g = r*2 + kr/72,
//                          kk = (kr%72)>>3, cg = kr&7, ci = g*8+cg; else zero pad.
__global__ __launch_bounds__(256) void prew_k(const float* __restrict__ w,
                                              _Float16* __restrict__ wp,
                                              int nct, int nkc, int mode,
                                              int ci_off, int cin_src)
{
    int idx = blockIdx.x * 256 + threadIdx.x;
    if (idx >= nct * nkc * 64) return;
    int lane = idx & 63;
    int kc = (idx >> 6) % nkc;
    int ct = (idx >> 6) / nkc;
    int m = lane & 15, quad = lane >> 4;
    int co = ct * 16 + m;
    union { half8 v; _Float16 e[8]; } ph, pl;
#pragma unroll
    for (int j = 0; j < 8; ++j) {
        int k = kc * 32 + quad * 8 + j;
        float f = 0.f;
        if (mode == 0) {
            int kk = k >> 6, ci = k & 63;
            f = w[((size_t)co * cin_src + ci_off + ci) * 9 + kk];
        } else {
            int r = k / 160, kr = k - r * 160;
            if (kr < 144) {
                int g = r * 2 + kr / 72;
                int rr = kr % 72;
                int kk = rr >> 3, cg = rr & 7;
                f = w[((size_t)co * cin_src + g * 8 + cg) * 9 + kk];
            }
        }
        _Float16 h = (_Float16)f;
        ph.e[j] = h; pl.e[j] = (_Float16)(f - (float)h);
    }
    size_t base = (size_t)((ct * nkc + kc) * 2) * 512;
    *(half8*)(wp + base + lane * 8) = ph.v;
    *(half8*)(wp + base + 512 + lane * 8) = pl.v;
}

// SPLIT-fp16 MFMA 3x3 conv, CHANNEL-LAST src & dst. Unchanged from R11 (proven):
// kc outer / ct inner, B-rows read once per kc, A-frags streamed JIT from L2.
template<int NCT, int SRCMODE, int ADD>
__global__ __launch_bounds__(256, 3) void mconv_k(
    const float* __restrict__ src, const float* __restrict__ R,
    const float* __restrict__ S, const _Float16* __restrict__ wp,
    const float* __restrict__ bias, float* __restrict__ out, int job0)
{
    constexpr int PL = 1456;              // 10*18*8 = 1440 + 16 pad (fp16 elems)
    constexpr int Ct = NCT * 16;
    const int jl = blockIdx.y, jg = job0 + jl;
    const int b = jg & 1;
    const int tile = blockIdx.x;          // 8 in x, 16 in y
    const int ty0 = (tile >> 3) << 3, tx0 = (tile & 7) << 4;
    const int tid = threadIdx.x;
    const int lane = tid & 63;
    const int wq = __builtin_amdgcn_readfirstlane(tid >> 6);
    const int n = lane & 15, quad = lane >> 4;

    const float* s0;
    if (SRCMODE == 0)      s0 = src + (size_t)jl * NC * HWP;
    else if (SRCMODE == 1) s0 = R + (size_t)b * NC * HWP;
    else                   s0 = S + (size_t)jl * NC * HWP;

    __shared__ _Float16 hh[8 * PL];
    __shared__ _Float16 ll[8 * PL];

    for (int t = tid; t < 360; t += 256) {
        int px = t >> 1, hf = t & 1;
        int hy = px / 18, hx = px - hy * 18;
        int gy = ty0 - 1 + hy, gx = tx0 - 1 + hx;
        bool ok = (gy >= 0 && gy < HH && gx >= 0 && gx < WW);
        const float* sp = s0 + (ok ? ((size_t)(gy * WW + gx) * 64) : 0) + hf * 32;
        int lb = px * 8;
#pragma unroll
        for (int c = 0; c < 4; ++c) {
            int cb = hf * 4 + c;
            floatx4 f0 = {0.f,0.f,0.f,0.f}, f1 = {0.f,0.f,0.f,0.f};
            if (ok) {
                f0 = *(const floatx4*)(sp + c * 8);
                f1 = *(const floatx4*)(sp + c * 8 + 4);
            }
            union { half8 v; _Float16 e[8]; } ph, pl;
#pragma unroll
            for (int j = 0; j < 4; ++j) {
                _Float16 h0 = (_Float16)f0[j], h1 = (_Float16)f1[j];
                ph.e[j] = h0;     ph.e[j+4] = h1;
                pl.e[j] = (_Float16)(f0[j] - (float)h0);
                pl.e[j+4] = (_Float16)(f1[j] - (float)h1);
            }
            *(half8*)&hh[cb * PL + lb] = ph.v;
            *(half8*)&ll[cb * PL + lb] = pl.v;
        }
    }
    __syncthreads();

    floatx4 acc0[NCT], acc1[NCT];
#pragma unroll
    for (int ct = 0; ct < NCT; ++ct) {
        acc0[ct] = floatx4{0.f, 0.f, 0.f, 0.f};
        acc1[ct] = floatx4{0.f, 0.f, 0.f, 0.f};
    }
    const int y0 = wq * 2, y1 = y0 + 1;
#pragma unroll
    for (int kc = 0; kc < NKC; ++kc) {
        const int kk = kc >> 1;
        const int dy = kk / 3, dx = kk % 3;
        const int cb = ((kc & 1) << 2) + quad;
        const int ix0 = cb * PL + ((y0 + dy) * 18 + n + dx) * 8;
        const int ix1 = cb * PL + ((y1 + dy) * 18 + n + dx) * 8;
        half8 B0h = *(const half8*)&hh[ix0];
        half8 B0l = *(const half8*)&ll[ix0];
        half8 B1h = *(const half8*)&hh[ix1];
        half8 B1l = *(const half8*)&ll[ix1];
        const _Float16* wk = wp + (size_t)kc * 1024 + lane * 8;
#pragma unroll
        for (int ct = 0; ct < NCT; ++ct) {
            const _Float16* wc = wk + (size_t)ct * NKC * 1024;
            half8 Ah = *(const half8*)wc;
            half8 Al = *(const half8*)(wc + 512);
            acc0[ct] = __builtin_amdgcn_mfma_f32_16x16x32_f16(Ah, B0h, acc0[ct], 0, 0, 0);
            acc0[ct] = __builtin_amdgcn_mfma_f32_16x16x32_f16(Ah, B0l, acc0[ct], 0, 0, 0);
            acc0[ct] = __builtin_amdgcn_mfma_f32_16x16x32_f16(Al, B0h, acc0[ct], 0, 0, 0);
            acc1[ct] = __builtin_amdgcn_mfma_f32_16x16x32_f16(Ah, B1h, acc1[ct], 0, 0, 0);
            acc1[ct] = __builtin_amdgcn_mfma_f32_16x16x32_f16(Ah, B1l, acc1[ct], 0, 0, 0);
            acc1[ct] = __builtin_amdgcn_mfma_f32_16x16x32_f16(Al, B1h, acc1[ct], 0, 0, 0);
        }
    }

    const int oy0 = ty0 + y0, oy1 = ty0 + y1, ox = tx0 + n;
#pragma unroll
    for (int ct = 0; ct < NCT; ++ct) {
        const floatx4 b4 = *(const floatx4*)(bias + ct * 16 + quad * 4);
        float* op0 = out + ((size_t)jl * HWP + (size_t)oy0 * WW + ox) * Ct
                         + ct * 16 + quad * 4;
        float* op1 = out + ((size_t)jl * HWP + (size_t)oy1 * WW + ox) * Ct
                         + ct * 16 + quad * 4;
        floatx4 v0 = acc0[ct], v1 = acc1[ct];
        if (ADD) {
            v0 += *(const floatx4*)op0;
            v1 += *(const floatx4*)op1;
        } else {
            v0 += b4;
            v1 += b4;
        }
        *(floatx4*)op0 = v0;
        *(floatx4*)op1 = v1;
    }
}

// Deformable conv, MFMA phase B (split-fp16). CHANNEL-LAST.
// R12: phase A LANE-PAIRED — two adjacent lanes split each (px,kk,g) task
// (lane 2l -> ch 0-3 of the group, 2l+1 -> ch 4-7): their 16-B corner accesses are
// address-adjacent in one wave-instruction -> TA coalesces to ONE transaction per
// corner (R11 profile: divergent-gather transaction rate was the bound, all pipes
// <30% busy). Weight/address math duplicated per pair (VALU had headroom).
// LDS sample writes are 4-B (sb stays 4-B aligned; SROW=166 keeps phase-B reads
// at free 2-way banking). Phase B unchanged (proven).
__global__ __launch_bounds__(256, 4) void mdeform_k(
    const float* __restrict__ in, const float* __restrict__ off,
    const _Float16* __restrict__ wp, const float* __restrict__ bias,
    float* __restrict__ out, int supp_mode, const float* __restrict__ S)
{
    constexpr int SROW = 166;
    const int jl = blockIdx.y;
    const int tile = blockIdx.x;          // 16x16 tiles of 8x8
    const int ty0 = (tile >> 4) << 3, tx0 = (tile & 15) << 3;
    const int tid = threadIdx.x;
    const int lane = tid & 63;
    const int q = __builtin_amdgcn_readfirstlane(tid >> 6);
    const int n = lane & 15, quad = lane >> 4;

    const float* ibase = supp_mode ? (S + (size_t)jl * NC * HWP)
                                   : (in + (size_t)jl * NC * HWP);
    const float* obase = off + (size_t)jl * OFFC * HWP;

    __shared__ _Float16 sh[64 * SROW];
    __shared__ _Float16 sl[64 * SROW];

    // zero pad K-slots [144,160)
    for (int e = tid; e < 64 * 16; e += 256) {
        int row = e >> 4, col = 144 + (e & 15);
        sh[row * SROW + col] = (_Float16)0.f;
        sl[row * SROW + col] = (_Float16)0.f;
    }

    floatx4 acc[4];
#pragma unroll
    for (int s = 0; s < 4; ++s) acc[s] = floatx4{0.f, 0.f, 0.f, 0.f};

    for (int r = 0; r < 4; ++r) {
        __syncthreads();
        // ---- phase A: lane-paired tasks. 2304 lane-tasks = 2 x (2 groups x 9 kk x 64 px)
        for (int i = 0; i < 9; ++i) {
            int idx = tid + (i << 8);         // 0..2303
            int hf = idx & 1;                 // which 4-channel half of the group
            int pair = idx >> 1;              // 0..1151
            int gl = pair / 576;
            int rem = pair - gl * 576;
            int kk = rem >> 6;
            int px = rem & 63;
            int g = r * 2 + gl;
            int yy = ty0 + (px >> 3), xx = tx0 + (px & 7);
            floatx2 o2 = *(const floatx2*)(obase + (size_t)(yy * WW + xx) * OFFC
                                           + (g * 9 + kk) * 2);
            float pyf = (float)(yy + (kk / 3) - 1) + o2[0];
            float pxf = (float)(xx + (kk % 3) - 1) + o2[1];
            float fy = floorf(pyf), fx = floorf(pxf);
            float wy = pyf - fy, wx = pxf - fx;
            int y0 = (int)fy, x0 = (int)fx;
            int y1 = y0 + 1, x1 = x0 + 1;
            float m00 = (y0 >= 0 && y0 < HH && x0 >= 0 && x0 < WW) ? 1.f : 0.f;
            float m01 = (y0 >= 0 && y0 < HH && x1 >= 0 && x1 < WW) ? 1.f : 0.f;
            float m10 = (y1 >= 0 && y1 < HH && x0 >= 0 && x0 < WW) ? 1.f : 0.f;
            float m11 = (y1 >= 0 && y1 < HH && x1 >= 0 && x1 < WW) ? 1.f : 0.f;
            float w00 = (1.f - wy) * (1.f - wx) * m00;
            float w01 = (1.f - wy) * wx * m01;
            float w10 = wy * (1.f - wx) * m10;
            float w11 = wy * wx * m11;
            int cy0 = min(max(y0, 0), HH - 1), cy1 = min(max(y1, 0), HH - 1);
            int cx0 = min(max(x0, 0), WW - 1), cx1 = min(max(x1, 0), WW - 1);
            const int co = g * 8 + hf * 4;    // channel offset of this lane's half
            const float* p00 = ibase + (size_t)(cy0 * WW + cx0) * 64 + co;
            const float* p01 = ibase + (size_t)(cy0 * WW + cx1) * 64 + co;
            const float* p10 = ibase + (size_t)(cy1 * WW + cx0) * 64 + co;
            const float* p11 = ibase + (size_t)(cy1 * WW + cx1) * 64 + co;
            floatx4 a = *(const floatx4*)p00;
            floatx4 b = *(const floatx4*)p01;
            floatx4 c = *(const floatx4*)p10;
            floatx4 d = *(const floatx4*)p11;
            floatx4 sv = a * w00 + b * w01 + c * w10 + d * w11;
            union { unsigned u[2]; _Float16 e[4]; } P, L;
#pragma unroll
            for (int j = 0; j < 4; ++j) {
                _Float16 h = (_Float16)sv[j];
                P.e[j] = h;
                L.e[j] = (_Float16)(sv[j] - (float)h);
            }
            int sb = px * SROW + gl * 72 + kk * 8 + hf * 4;   // even -> 4-B aligned
            unsigned* shp = (unsigned*)&sh[sb];
            unsigned* slp = (unsigned*)&sl[sb];
            shp[0] = P.u[0]; shp[1] = P.u[1];
            slp[0] = L.u[0]; slp[1] = L.u[1];
        }
        __syncthreads();
        // ---- phase B: MFMA contraction, wave q -> co-tile q ----
#pragma unroll
        for (int kc5 = 0; kc5 < 5; ++kc5) {
            int kcg = r * 5 + kc5;
            size_t base = (size_t)((q * 20 + kcg) * 2) * 512;
            half8 Ah = *(const half8*)(wp + base + lane * 8);
            half8 Al = *(const half8*)(wp + base + 512 + lane * 8);
#pragma unroll
            for (int s = 0; s < 4; ++s) {
                int px = s * 16 + n;
                const int ix = px * SROW + kc5 * 32 + quad * 8;
                half8 Bh = *(const half8*)&sh[ix];
                half8 Bl = *(const half8*)&sl[ix];
                acc[s] = __builtin_amdgcn_mfma_f32_16x16x32_f16(Ah, Bh, acc[s], 0, 0, 0);
                acc[s] = __builtin_amdgcn_mfma_f32_16x16x32_f16(Ah, Bl, acc[s], 0, 0, 0);
                acc[s] = __builtin_amdgcn_mfma_f32_16x16x32_f16(Al, Bh, acc[s], 0, 0, 0);
            }
        }
    }
    const floatx4 b4 = *(const floatx4*)(bias + q * 16 + quad * 4);
#pragma unroll
    for (int s = 0; s < 4; ++s) {
        int px = s * 16 + n;
        int oy = ty0 + (px >> 3), ox = tx0 + (px & 7);
        float* op = out + ((size_t)jl * HWP + (size_t)oy * WW + ox) * 64
                        + q * 16 + quad * 4;
        *(floatx4*)op = acc[s] + b4;
    }
}

// rec conv (64 -> 3): fp32, channel-last input. Writes d_out (planar).
__global__ __launch_bounds__(256) void conv3x3_rec_k(
    const float* __restrict__ in, const float* __restrict__ w,
    const float* __restrict__ bias, float* __restrict__ out, int job0)
{
    constexpr int CB = 8;
    constexpr int PITCH = 48;
    constexpr int CH = 18 * PITCH;
    const int jl = blockIdx.y, jg = job0 + jl;
    const int b = jg & 1, fi = jg >> 1;
    const int frame = fi + (fi >= 2 ? 1 : 0);
    const int tile = blockIdx.x;
    const int ty0 = (tile >> 3) << 4, tx0 = (tile & 7) << 4;
    const int tid = threadIdx.x;
    const int tx = tid & 15, ty = tid >> 4;
    const float* srcA = in + (size_t)jl * NC * HWP;

    __shared__ float lds[CB * CH];
    float acc[3] = {bias[0], bias[1], bias[2]};

    for (int cb = 0; cb < NC; cb += CB) {
        __syncthreads();
        for (int e = tid; e < CB * 324; e += 256) {
            int c = e & 7;
            int r = e >> 3;
            int iy = r / 18, ix = r - iy * 18;
            int gy = ty0 - 1 + iy, gx = tx0 - 1 + ix;
            float v = 0.f;
            if (gy >= 0 && gy < HH && gx >= 0 && gx < WW)
                v = srcA[(size_t)(gy * WW + gx) * 64 + cb + c];
            lds[c * CH + iy * PITCH + ix] = v;
        }
        __syncthreads();
#pragma unroll
        for (int c = 0; c < CB; ++c) {
            float t[9];
#pragma unroll
            for (int dy = 0; dy < 3; ++dy)
#pragma unroll
                for (int dx = 0; dx < 3; ++dx)
                    t[dy * 3 + dx] = lds[c * CH + (ty + dy) * PITCH + (tx + dx)];
            int ci = cb + c;
#pragma unroll
            for (int o = 0; o < 3; ++o) {
                const float* wo = w + ((size_t)o * NC + ci) * 9;
#pragma unroll
                for (int kk = 0; kk < 9; ++kk)
                    acc[o] = fmaf(wo[kk], t[kk], acc[o]);
            }
        }
    }
    const int oy = ty0 + ty, ox = tx0 + tx;
#pragma unroll
    for (int o = 0; o < 3; ++o)
        out[((size_t)(b * NN + frame) * 3 + o) * HWP + oy * WW + ox] = acc[o];
}

extern "C" void kernel_launch(void* const* d_in, const int* in_sizes, int n_in,
                              void* d_out, int out_size, void* d_ws, size_t ws_size,
                              hipStream_t stream)
{
    const float* pf    = (const float*)d_in[0];
    const float* xc    = (const float*)d_in[1];
    const float* cr_w  = (const float*)d_in[2];
    const float* cr_b  = (const float*)d_in[3];
    const float* ow[4] = {(const float*)d_in[4],  (const float*)d_in[8],
                          (const float*)d_in[12], (const float*)d_in[16]};
    const float* ob[4] = {(const float*)d_in[5],  (const float*)d_in[9],
                          (const float*)d_in[13], (const float*)d_in[17]};
    const float* dw[4] = {(const float*)d_in[6],  (const float*)d_in[10],
                          (const float*)d_in[14], (const float*)d_in[18]};
    const float* db[4] = {(const float*)d_in[7],  (const float*)d_in[11],
                          (const float*)d_in[15], (const float*)d_in[19]};
    const float* rec_w = (const float*)d_in[20];
    const float* rec_b = (const float*)d_in[21];
    float* out = (float*)d_out;

    // ws layout: [wp cr x2][wp of x4][wp dc x4][R 2][S JC][A JC][Bb JC][O JC]
    const size_t WPC = (size_t)4 * NKC * 1024;
    const size_t WPO = (size_t)9 * NKC * 1024;
    const size_t WPD = (size_t)4 * 20 * 1024;
    _Float16* wp_cr0 = (_Float16*)d_ws;
    _Float16* wp_cr1 = wp_cr0 + WPC;
    _Float16* wp_of[4];
    _Float16* wp_dc[4];
    _Float16* curh = wp_cr1 + WPC;
    for (int i = 0; i < 4; ++i) { wp_of[i] = curh; curh += WPO; }
    for (int i = 0; i < 4; ++i) { wp_dc[i] = curh; curh += WPD; }
    size_t wp_bytes = (size_t)((char*)curh - (char*)d_ws);

    const size_t fplane = (size_t)NC * HWP;
    const size_t oplane = (size_t)OFFC * HWP;
    int JC = 8;
    while (JC > 1 &&
           wp_bytes + (2 + 3 * (size_t)JC) * fplane * 4 + (size_t)JC * oplane * 4 > ws_size)
        JC >>= 1;
    float* R  = (float*)curh;
    float* S  = R  + 2 * fplane;
    float* A  = S  + (size_t)JC * fplane;
    float* Bb = A  + (size_t)JC * fplane;
    float* O  = Bb + (size_t)JC * fplane;

    // ---- weight preprocessing + ref repack (every call; ws re-poisoned) ----
    {
        int nc4 = 4 * NKC * 64, nc9 = 9 * NKC * 64, ncd = 4 * 20 * 64;
        dim3 b4((nc4 + 255) / 256), b9((nc9 + 255) / 256), bd((ncd + 255) / 256);
        prew_k<<<b4, 256, 0, stream>>>(cr_w, wp_cr0, 4, NKC, 0, 0, 128);
        prew_k<<<b4, 256, 0, stream>>>(cr_w, wp_cr1, 4, NKC, 0, 64, 128);
        for (int i = 0; i < 4; ++i) {
            prew_k<<<b9, 256, 0, stream>>>(ow[i], wp_of[i], 9, NKC, 0, 0, 64);
            prew_k<<<bd, 256, 0, stream>>>(dw[i], wp_dc[i], 4, 20, 1, 0, 64);
        }
        repack_k<<<dim3(256, 2), 256, 0, stream>>>(pf, R, 0, 1);
    }

    copy_center_k<<<dim3((NB * 3 * HWP + 255) / 256), 256, 0, stream>>>(xc, out);

    for (int job0 = 0; job0 < 8; job0 += JC) {
        dim3 blk(256);
        dim3 gconv(128, JC), gdef(256, JC), grec(64, JC);
        repack_k<<<dim3(256, JC), blk, 0, stream>>>(pf, S, job0, 0);
        // fea1 = cr_conv(concat(ref, supp)) : two K=576 passes (ref, then supp ADD)
        mconv_k<4, 1, 0><<<gconv, blk, 0, stream>>>(nullptr, R, S, wp_cr0, cr_b, A, job0);
        mconv_k<4, 2, 1><<<gconv, blk, 0, stream>>>(nullptr, R, S, wp_cr1, cr_b, A, job0);
        // off1(fea1); fea2 = deform(fea1)
        mconv_k<9, 0, 0><<<gconv, blk, 0, stream>>>(A, R, S, wp_of[0], ob[0], O, job0);
        mdeform_k<<<gdef, blk, 0, stream>>>(A, O, wp_dc[0], db[0], Bb, 0, S);
        // off2(fea2); fea3 = deform(fea2)
        mconv_k<9, 0, 0><<<gconv, blk, 0, stream>>>(Bb, R, S, wp_of[1], ob[1], O, job0);
        mdeform_k<<<gdef, blk, 0, stream>>>(Bb, O, wp_dc[1], db[1], A, 0, S);
        // off3(fea3); fea4 = deform(supp)
        mconv_k<9, 0, 0><<<gconv, blk, 0, stream>>>(A, R, S, wp_of[2], ob[2], O, job0);
        mdeform_k<<<gdef, blk, 0, stream>>>(nullptr, O, wp_dc[2], db[2], Bb, 1, S);
        // off4(fea4); aligned = deform(fea4)
        mconv_k<9, 0, 0><<<gconv, blk, 0, stream>>>(Bb, R, S, wp_of[3], ob[3], O, job0);
        mdeform_k<<<gdef, blk, 0, stream>>>(Bb, O, wp_dc[3], db[3], A, 0, S);
        // out[b, frame] = rec_conv(aligned)
        conv3x3_rec_k<<<grec, blk, 0, stream>>>(A, rec_w, rec_b, out, job0);
    }
}